// Round 7
// baseline (224.407 us; speedup 1.0000x reference)
//
#include <hip/hip_runtime.h>
#include <hip/hip_bf16.h>

#define B_SZ 4
#define T_SEQ 1024
#define DM 128
#define ED_ 256
#define NS 64
#define LOG2E 1.44269504088896340736f

// workspace layout (float elements). Total = 6,389,760 floats = 25.6 MB (accepted size).
// dxpT is TRANSPOSED [b][e][t] x {delta, delta*xs}; yrT is TRANSPOSED [b][e][t].
#define OFF_Z      0u         /* 524288  f32  z (residual, read by K6)            */
#define OFF_ZG     524288u    /* 1048576 f32  gate (k2 -> k6)                     */
#define OFF_XSR    1572864u   /* 1048576 f32  conv input (k2 -> k4b)              */
#define OFF_WC     2621440u   /* 98304   f32  combined x_proj/dt weight (384x256) */
#define OFF_YR     2719744u   /* 1048576 f32  scan output, [b][e][t] (k5 -> k6)   */
#define OFF_DPX    3768320u   /* 2097152 f32  {delta, delta*xs} [b][e][t] pairs   */
#define OFF_BC     5865472u   /* 524288  f32  {B, C} [b][t][n] pairs (k4b -> k5)  */

__device__ __forceinline__ float sigmoidf_(float x){ return 1.f/(1.f+__expf(-x)); }
__device__ __forceinline__ float exp2_(float x){ return __builtin_amdgcn_exp2f(x); }
__device__ __forceinline__ float rlane_(float v, int l){
  return __int_as_float(__builtin_amdgcn_readlane(__float_as_int(v), l));
}
// collect: accI[lane t] = total of pp (total sits in lane 63 after DPP6).
// v_writelane may read only ONE SGPR (constant-bus rule) -> lane select must be
// an IMMEDIATE. All call sites pass t = unrolled-loop constant, so "i" folds.
__device__ __forceinline__ void collect_(int &accI, float pp, int t){
  int s;
  asm("v_readlane_b32 %0, %1, 63" : "=s"(s) : "v"(__float_as_int(pp)));
  asm("v_writelane_b32 %0, %1, %2" : "+v"(accI) : "s"(s), "i"(t));
}

// Fused DPP add: p += dpp(p) in ONE instruction. bound_ctrl:0 => invalid lanes read 0.
#define DPPR(p, ctl) asm("v_add_f32_dpp %0, %0, %0 " ctl " row_mask:0xf bank_mask:0xf bound_ctrl:0" : "+v"(p))
#define DPP6(p) do{ DPPR(p,"row_shr:1"); DPPR(p,"row_shr:2"); DPPR(p,"row_shr:4"); \
                    DPPR(p,"row_shr:8"); DPPR(p,"row_bcast:15"); DPPR(p,"row_bcast:31"); }while(0)

// K2f: blocks 0..511: fused [z = zseq+aux@auxW.T+auxb ; zn=RMSNorm(z)*rms_w] -> LDS,
//      then xz = zn @ in_proj_W.T -> xsr | zg. blocks 512..895: build Wc.
__global__ __launch_bounds__(256) void k2_fused(const float* zseq, const float* aux, const float* auxW,
                                                const float* auxb, const float* rmsw, const float* W,
                                                const float* xprojW, const float* dtW,
                                                float* z, float* xsr, float* zg, float* Wc){
  if (blockIdx.x >= 512){
    int r = blockIdx.x - 512; int k = threadIdx.x;
    float v;
    if (r < 256){
      v = 0.f;
      #pragma unroll
      for (int j=0;j<8;j++) v += dtW[r*8+j] * xprojW[j*256+k];
    } else {
      v = xprojW[(8 + r-256)*256 + k];
    }
    Wc[r*256+k] = v;
    return;
  }
  __shared__ float at[128][8];
  int bt0 = blockIdx.x*8; int tid = threadIdx.x;
  {
    int r = tid>>5, l = tid&31;
    int bt = bt0 + r;
    float a0 = aux[bt*3+0], a1 = aux[bt*3+1], a2 = aux[bt*3+2];
    float zv[4]; float ssq = 0.f;
    #pragma unroll
    for (int j=0;j<4;j++){
      int d = l + 32*j;
      float v = zseq[bt*DM+d] + a0*auxW[d*3+0] + a1*auxW[d*3+1] + a2*auxW[d*3+2] + auxb[d];
      zv[j] = v; ssq += v*v;
    }
    #pragma unroll
    for (int m=16;m>=1;m>>=1) ssq += __shfl_xor(ssq, m);
    float rinv = rsqrtf(ssq*(1.f/DM) + 1e-5f);
    #pragma unroll
    for (int j=0;j<4;j++){
      int d = l + 32*j;
      z[bt*DM+d] = zv[j];
      at[d][r] = zv[j]*rinv*rmsw[d];
    }
  }
  __syncthreads();
  float acc0[8], acc1[8];
  #pragma unroll
  for (int r=0;r<8;r++){ acc0[r]=0.f; acc1[r]=0.f; }
  int c0 = tid, c1 = tid+256;
  for (int k=0;k<128;k+=4){
    float4 w0v = *(const float4*)(W + c0*128 + k);
    float4 w1v = *(const float4*)(W + c1*128 + k);
    float w0[4] = {w0v.x, w0v.y, w0v.z, w0v.w};
    float w1[4] = {w1v.x, w1v.y, w1v.z, w1v.w};
    #pragma unroll
    for (int kk=0;kk<4;kk++){
      float a[8];
      *(float4*)&a[0] = *(const float4*)&at[k+kk][0];
      *(float4*)&a[4] = *(const float4*)&at[k+kk][4];
      #pragma unroll
      for (int r=0;r<8;r++){ acc0[r] = fmaf(a[r], w0[kk], acc0[r]); acc1[r] = fmaf(a[r], w1[kk], acc1[r]); }
    }
  }
  #pragma unroll
  for (int r=0;r<8;r++){
    int bt = bt0+r;
    xsr[bt*ED_ + c0] = acc0[r];
    zg [bt*ED_ + c0] = acc1[r];
  }
}

// K4b: conv(k=4)+bias+SiLU from xsr (LDS), then [delta_pre | B | C] = xs @ Wc.T.
// Outputs: dxpT[b][e][t] = {delta, delta*xs} (transposed, 64B/thread segments);
//          bcp[b][t][n]  = {B, C}.
__global__ __launch_bounds__(384) void k4b_xproj(const float* xsr, const float* convW, const float* convb,
                                                 const float* Wc, const float* dtb,
                                                 float* dxp, float* bcf){
  __shared__ float at[256][8];
  int bt0 = blockIdx.x*8; int tid = threadIdx.x;
  for (int i=tid;i<2048;i+=384){
    int r=i>>8,k=i&255; int bt=bt0+r; int t = bt & (T_SEQ-1);
    float4 wv = *(const float4*)(convW + k*4);
    float s = convb[k];
    if (t>=3) s += xsr[(bt-3)*ED_+k]*wv.x;
    if (t>=2) s += xsr[(bt-2)*ED_+k]*wv.y;
    if (t>=1) s += xsr[(bt-1)*ED_+k]*wv.z;
    s += xsr[bt*ED_+k]*wv.w;
    at[k][r] = s * sigmoidf_(s);
  }
  __syncthreads();
  float acc[8];
  #pragma unroll
  for (int r=0;r<8;r++) acc[r]=0.f;
  int c = tid;
  for (int k=0;k<256;k+=4){
    float4 wv = *(const float4*)(Wc + c*256 + k);
    float w[4] = {wv.x, wv.y, wv.z, wv.w};
    #pragma unroll
    for (int kk=0;kk<4;kk++){
      float a[8];
      *(float4*)&a[0] = *(const float4*)&at[k+kk][0];
      *(float4*)&a[4] = *(const float4*)&at[k+kk][4];
      #pragma unroll
      for (int r=0;r<8;r++) acc[r] = fmaf(a[r], w[kk], acc[r]);
    }
  }
  int b4 = bt0 >> 10, tb = bt0 & (T_SEQ-1);
  if (c < 256){
    float bcv = dtb[c];
    float2* pout = (float2*)dxp + (size_t)(b4*ED_ + c)*T_SEQ + tb;
    #pragma unroll
    for (int r=0;r<8;r++){
      float xv = acc[r] + bcv;
      float dv = (xv > 20.f) ? xv : log1pf(__expf(xv));
      pout[r] = make_float2(dv, dv * at[c][r]);   // {delta, delta*xs}
    }
  } else if (c < 320){
    #pragma unroll
    for (int r=0;r<8;r++) bcf[((size_t)(bt0+r)*NS + (c-256))*2 + 0] = acc[r];
  } else {
    #pragma unroll
    for (int r=0;r<8;r++) bcf[((size_t)(bt0+r)*NS + (c-320))*2 + 1] = acc[r];
  }
}

// K5: chunked scan. R6 structure (lane=t dxp loads + readlane broadcast +
// DPP6 reduce + writelane collect) but 8 WAVES x 128-t CHUNKS per block
// (512 thr, launch_bounds(512,8) -> 8 waves/SIMD, 2x the TLP of R6's 4).
// Rationale (R6 counters): VALUBusy 56%, Occupancy 32%, dur 64us -> ~28us of
// stall with only 4 waves/SIMD; bc-load latency + L2 stream (~0.9GB/launch)
// needs more resident waves. VGPR demand is now ~50 < cap 64, so the R2
// (512,8)-collapse pathology (demand 90 >> cap) does not apply.
__global__ __launch_bounds__(512,8) void k5_scan(const float* dxpf, const float* bcf,
                                                  const float* Alog, float* yrT){
  __shared__ float lcar[7][64], lapr[7][64];
  int i = blockIdx.x;
  int w = threadIdx.x >> 6;      // chunk 0..7
  int n = threadIdx.x & 63;      // state index (lane)
  int x = i & 7;                 // XCD swizzle
  int r = i >> 3;
  int b = r & 3;
  int g = r >> 2;                // 0..31
  int e = x*32 + g;
  const int CH = T_SEQ/8;        // 128
  int t0 = w*CH;
  float A2 = -__expf(Alog[e*NS+n]) * LOG2E;
  const float2* pd  = (const float2*)dxpf + (size_t)(b*ED_ + e)*T_SEQ + t0;  // lane=t
  const float2* pbc = (const float2*)bcf  + (size_t)(b*T_SEQ + t0)*NS + n;   // lane=n
  float*        py  = yrT + (size_t)(b*ED_ + e)*T_SEQ + t0;

  // ---- phase 1: carry-only scan (waves 0..6; wave 7's carry unused)
  if (w < 7){
    float h = 0.f, Ssum = 0.f;
    float2 dxc = pd[n];
    for (int sb=0; sb<CH; sb+=64){
      float2 dxn = dxc;
      if (sb+64 < CH) dxn = pd[sb+64+n];
      float sv = dxc.x;
      DPP6(sv);
      Ssum += rlane_(sv, 63);
      float bA[8], bB[8];
      #pragma unroll
      for (int j=0;j<8;j++) bA[j] = pbc[(sb+j)*NS].x;
      #pragma unroll
      for (int bb=0; bb<64; bb+=16){
        #pragma unroll
        for (int j=0;j<8;j++) bB[j] = pbc[(sb+bb+8+j)*NS].x;
        #pragma unroll
        for (int j=0;j<8;j++){
          float sd = rlane_(dxc.x, bb+j);
          float su = rlane_(dxc.y, bb+j);
          h = fmaf(exp2_(sd*A2), h, su*bA[j]);
        }
        if (bb+16 < 64){
          #pragma unroll
          for (int j=0;j<8;j++) bA[j] = pbc[(sb+bb+16+j)*NS].x;
        }
        #pragma unroll
        for (int j=0;j<8;j++){
          float sd = rlane_(dxc.x, bb+8+j);
          float su = rlane_(dxc.y, bb+8+j);
          h = fmaf(exp2_(sd*A2), h, su*bB[j]);
        }
      }
      dxc = dxn;
    }
    lcar[w][n] = h;
    lapr[w][n] = exp2_(A2*Ssum);
  }
  __syncthreads();

  // ---- combine: h_in for this wave's chunk (uniform branch per wave)
  float h = 0.f;
  if (w >= 1) h = lcar[0][n];
  #pragma unroll
  for (int q=1;q<7;q++) if (w > q) h = fmaf(lapr[q][n], h, lcar[q][n]);

  // ---- phase 2: full output scan
  {
    float2 dxc = pd[n];
    for (int sb=0; sb<CH; sb+=64){
      float2 dxn = dxc;
      if (sb+64 < CH) dxn = pd[sb+64+n];
      int accI = 0;
      float2 cA[8], cB[8];
      #pragma unroll
      for (int j=0;j<8;j++) cA[j] = pbc[(sb+j)*NS];
      #pragma unroll
      for (int bb=0; bb<64; bb+=16){
        #pragma unroll
        for (int j=0;j<8;j++) cB[j] = pbc[(sb+bb+8+j)*NS];
        #pragma unroll
        for (int j=0;j<8;j++){
          float sd = rlane_(dxc.x, bb+j);
          float su = rlane_(dxc.y, bb+j);
          h = fmaf(exp2_(sd*A2), h, su*cA[j].x);
          float pp = h*cA[j].y;
          DPP6(pp);
          collect_(accI, pp, bb+j);
        }
        if (bb+16 < 64){
          #pragma unroll
          for (int j=0;j<8;j++) cA[j] = pbc[(sb+bb+16+j)*NS];
        }
        #pragma unroll
        for (int j=0;j<8;j++){
          float sd = rlane_(dxc.x, bb+8+j);
          float su = rlane_(dxc.y, bb+8+j);
          h = fmaf(exp2_(sd*A2), h, su*cB[j].x);
          float pp = h*cB[j].y;
          DPP6(pp);
          collect_(accI, pp, bb+8+j);
        }
      }
      py[sb+n] = __int_as_float(accI);
      dxc = dxn;
    }
  }
}

// K6: stage yrT (e-major) + xs = u/delta from dxpT via LDS; combine with gate;
// then out = LayerNorm(y @ out_proj_W.T + 2*z)*ln_w + ln_b.
__global__ __launch_bounds__(256) void k6_out(const float* yrT, const float* dxpf, const float* zg,
                                               const float* Dp, const float* W, const float* z,
                                               const float* lnw, const float* lnb, float* out){
  __shared__ float yt[256][8];
  __shared__ float xst[256][8];
  __shared__ float psum[4][4], psq[4][4];
  int bt0 = blockIdx.x*8; int tid = threadIdx.x;
  int b4 = bt0 >> 10, tb = bt0 & (T_SEQ-1);
  int el = tid>>3, tl = tid&7;
  #pragma unroll
  for (int gg=0; gg<8; gg++){
    int ee = el + gg*32;
    size_t base = (size_t)(b4*ED_ + ee)*T_SEQ + tb + tl;
    float2 du = ((const float2*)dxpf)[base];
    yt[ee][tl]  = yrT[base];
    xst[ee][tl] = du.y / du.x;        // xs = (delta*xs)/delta; delta >= softplus(-4) ~ 0.018
  }
  __syncthreads();
  for (int i=tid;i<2048;i+=256){
    int rr=i>>8, k=i&255; int bt=bt0+rr;
    float zgv = zg[bt*ED_ + k];
    float yv  = yt[k][rr] + Dp[k]*xst[k][rr];
    yt[k][rr] = yv * zgv * sigmoidf_(zgv);
  }
  __syncthreads();
  int d = tid & 127, gdx = tid>>7;
  float acc[4] = {0.f,0.f,0.f,0.f};
  for (int k=0;k<256;k+=4){
    float4 wv = *(const float4*)(W + d*256 + k);
    float w[4] = {wv.x, wv.y, wv.z, wv.w};
    #pragma unroll
    for (int kk=0;kk<4;kk++){
      float4 q = *(const float4*)&yt[k+kk][gdx*4];
      acc[0] = fmaf(q.x, w[kk], acc[0]);
      acc[1] = fmaf(q.y, w[kk], acc[1]);
      acc[2] = fmaf(q.z, w[kk], acc[2]);
      acc[3] = fmaf(q.w, w[kk], acc[3]);
    }
  }
  float val[4];
  #pragma unroll
  for (int j=0;j<4;j++){
    int bt = bt0 + gdx*4 + j;
    val[j] = acc[j] + 2.f*z[bt*DM + d];
  }
  int w_id = tid>>6;
  #pragma unroll
  for (int j=0;j<4;j++){
    float s = val[j], q = val[j]*val[j];
    #pragma unroll
    for (int off=32; off>=1; off>>=1){ s += __shfl_down(s, off); q += __shfl_down(q, off); }
    if ((tid&63)==0){ psum[w_id][j]=s; psq[w_id][j]=q; }
  }
  __syncthreads();
  float lw = lnw[d], lb = lnb[d];
  #pragma unroll
  for (int j=0;j<4;j++){
    int bt = bt0 + gdx*4 + j;
    float sum = psum[gdx*2][j] + psum[gdx*2+1][j];
    float sq  = psq [gdx*2][j] + psq [gdx*2+1][j];
    float mu  = sum*(1.f/DM);
    float var = sq*(1.f/DM) - mu*mu;
    float inv = rsqrtf(var + 1e-5f);
    out[bt*DM + d] = (val[j]-mu)*inv*lw + lb;
  }
}

extern "C" void kernel_launch(void* const* d_in, const int* in_sizes, int n_in,
                              void* d_out, int out_size, void* d_ws, size_t ws_size,
                              hipStream_t stream){
  const float* zseq = (const float*)d_in[0];
  const float* aux  = (const float*)d_in[1];
  const float* auxW = (const float*)d_in[2];
  const float* auxb = (const float*)d_in[3];
  const float* lnw  = (const float*)d_in[4];
  const float* lnb  = (const float*)d_in[5];
  const float* rmsw = (const float*)d_in[6];
  const float* inW  = (const float*)d_in[7];
  const float* convW= (const float*)d_in[8];
  const float* convb= (const float*)d_in[9];
  const float* xpW  = (const float*)d_in[10];
  const float* dtW  = (const float*)d_in[11];
  const float* dtb  = (const float*)d_in[12];
  const float* Alog = (const float*)d_in[13];
  const float* Dp   = (const float*)d_in[14];
  const float* outW = (const float*)d_in[15];
  float* out = (float*)d_out;
  float* ws = (float*)d_ws;

  float* z   = ws+OFF_Z;
  float* zg  = ws+OFF_ZG;
  float* xsr = ws+OFF_XSR;
  float* Wc  = ws+OFF_WC;
  float* yr  = ws+OFF_YR;
  float* dxp = ws+OFF_DPX;
  float* bcp = ws+OFF_BC;

  k2_fused <<<896,256,0,stream>>>(zseq,aux,auxW,auxb,rmsw,inW,xpW,dtW,z,xsr,zg,Wc);
  k4b_xproj<<<512,384,0,stream>>>(xsr,convW,convb,Wc,dtb,dxp,bcp);
  k5_scan  <<<1024,512,0,stream>>>(dxp,bcp,Alog,yr);
  k6_out   <<<512,256,0,stream>>>(yr,dxp,zg,Dp,outW,z,lnw,lnb,out);
}

// Round 9
// 208.074 us; speedup vs baseline: 1.0785x; 1.0785x over previous
//
#include <hip/hip_runtime.h>
#include <hip/hip_bf16.h>

#define B_SZ 4
#define T_SEQ 1024
#define DM 128
#define ED_ 256
#define NS 64
#define LOG2E 1.44269504088896340736f

// workspace layout (float elements). Total = 6,389,760 floats = 25.6 MB (accepted size).
// dxpT is TRANSPOSED [b][e][t] x {delta, delta*xs}; yrT is TRANSPOSED [b][e][t].
// WTi (in_proj transposed, 64K floats) lives in the FRONT of the YR region:
// written by k0, read by k2 (both complete before k5 overwrites YR; stream-serial).
#define OFF_Z      0u         /* 524288  f32  z (residual, read by K6)            */
#define OFF_ZG     524288u    /* 1048576 f32  gate (k2 -> k6)                     */
#define OFF_XSR    1572864u   /* 1048576 f32  conv input (k2 -> k4b)              */
#define OFF_WC     2621440u   /* 98304   f32  WcT[k][c] transposed combined wt    */
#define OFF_YR     2719744u   /* 1048576 f32  scan out [b][e][t]; head hosts WTi  */
#define OFF_DPX    3768320u   /* 2097152 f32  {delta, delta*xs} [b][e][t] pairs   */
#define OFF_BC     5865472u   /* 524288  f32  {B, C} [b][t][n] pairs (k4b -> k5)  */

__device__ __forceinline__ float sigmoidf_(float x){ return 1.f/(1.f+__expf(-x)); }
__device__ __forceinline__ float exp2_(float x){ return __builtin_amdgcn_exp2f(x); }
__device__ __forceinline__ float rlane_(float v, int l){
  return __int_as_float(__builtin_amdgcn_readlane(__float_as_int(v), l));
}
// collect: accI[lane t] = total of pp (total sits in lane 63 after DPP6).
// v_writelane reads ONE SGPR max -> lane select must be an immediate.
__device__ __forceinline__ void collect_(int &accI, float pp, int t){
  int s;
  asm("v_readlane_b32 %0, %1, 63" : "=s"(s) : "v"(__float_as_int(pp)));
  asm("v_writelane_b32 %0, %1, %2" : "+v"(accI) : "s"(s), "i"(t));
}

// Fused DPP add: p += dpp(p) in ONE instruction. bound_ctrl:0 => invalid lanes read 0.
#define DPPR(p, ctl) asm("v_add_f32_dpp %0, %0, %0 " ctl " row_mask:0xf bank_mask:0xf bound_ctrl:0" : "+v"(p))
#define DPP6(p) do{ DPPR(p,"row_shr:1"); DPPR(p,"row_shr:2"); DPPR(p,"row_shr:4"); \
                    DPPR(p,"row_shr:8"); DPPR(p,"row_bcast:15"); DPPR(p,"row_bcast:31"); }while(0)

// K0: transpose in_proj W (512x128 row-major) -> WTi[k][c] (128x512).
// Reads strided (one-off 256KB, negligible); writes coalesced.
__global__ __launch_bounds__(256) void k0_t(const float* W, float* WTi){
  int k = blockIdx.x;        // 0..127
  int c = threadIdx.x;       // 0..255
  WTi[k*512 + c]       = W[(size_t)c*128 + k];
  WTi[k*512 + c + 256] = W[(size_t)(c+256)*128 + k];
}

// K2f: blocks 0..511: fused [z = zseq+aux@auxW.T+auxb ; zn=RMSNorm(z)*rms_w] -> LDS,
//      then xz = zn @ in_proj_W.T -> xsr | zg, reading WTi[k][c] COALESCED
//      (R7 theory: per-thread-row W reads = 64 cache lines/instr = request-bound).
//      blocks 512..895: build WcT[k][c] (transposed combined x_proj/dt weight).
__global__ __launch_bounds__(256) void k2_fused(const float* zseq, const float* aux, const float* auxW,
                                                const float* auxb, const float* rmsw, const float* WTi,
                                                const float* xprojW, const float* dtW,
                                                float* z, float* xsr, float* zg, float* WcT){
  if (blockIdx.x >= 512){
    int r = blockIdx.x - 512; int k = threadIdx.x;
    float v;
    if (r < 256){
      v = 0.f;
      #pragma unroll
      for (int j=0;j<8;j++) v += dtW[r*8+j] * xprojW[j*256+k];
    } else {
      v = xprojW[(8 + r-256)*256 + k];
    }
    WcT[k*384 + r] = v;      // transposed store (uncoalesced but one-off)
    return;
  }
  __shared__ float at[128][8];
  int bt0 = blockIdx.x*8; int tid = threadIdx.x;
  {
    int r = tid>>5, l = tid&31;
    int bt = bt0 + r;
    float a0 = aux[bt*3+0], a1 = aux[bt*3+1], a2 = aux[bt*3+2];
    float zv[4]; float ssq = 0.f;
    #pragma unroll
    for (int j=0;j<4;j++){
      int d = l + 32*j;
      float v = zseq[bt*DM+d] + a0*auxW[d*3+0] + a1*auxW[d*3+1] + a2*auxW[d*3+2] + auxb[d];
      zv[j] = v; ssq += v*v;
    }
    #pragma unroll
    for (int m=16;m>=1;m>>=1) ssq += __shfl_xor(ssq, m);
    float rinv = rsqrtf(ssq*(1.f/DM) + 1e-5f);
    #pragma unroll
    for (int j=0;j<4;j++){
      int d = l + 32*j;
      z[bt*DM+d] = zv[j];
      at[d][r] = zv[j]*rinv*rmsw[d];
    }
  }
  __syncthreads();
  float acc0[8], acc1[8];
  #pragma unroll
  for (int r=0;r<8;r++){ acc0[r]=0.f; acc1[r]=0.f; }
  int c0 = tid;
  for (int k=0;k<128;k++){
    float w0 = WTi[k*512 + c0];          // coalesced: lanes -> consecutive floats
    float w1 = WTi[k*512 + c0 + 256];
    float a[8];
    *(float4*)&a[0] = *(const float4*)&at[k][0];   // broadcast b128 (conflict-free)
    *(float4*)&a[4] = *(const float4*)&at[k][4];
    #pragma unroll
    for (int r=0;r<8;r++){ acc0[r] = fmaf(a[r], w0, acc0[r]); acc1[r] = fmaf(a[r], w1, acc1[r]); }
  }
  #pragma unroll
  for (int r=0;r<8;r++){
    int bt = bt0+r;
    xsr[bt*ED_ + c0] = acc0[r];
    zg [bt*ED_ + c0] = acc1[r];
  }
}

// K4b: conv(k=4)+bias+SiLU from xsr (LDS), then [delta_pre | B | C] = xs @ WcT.
// Weight reads COALESCED (WcT[k][c], c=tid). Output writes are R7's exact
// harness-proven code (LDS-staged variant from R8 removed pending crash triage).
__global__ __launch_bounds__(384) void k4b_xproj(const float* xsr, const float* convW, const float* convb,
                                                 const float* WcT, const float* dtb,
                                                 float* dxp, float* bcf){
  __shared__ float at[256][8];
  int bt0 = blockIdx.x*8; int tid = threadIdx.x;
  for (int i=tid;i<2048;i+=384){
    int r=i>>8,k=i&255; int bt=bt0+r; int t = bt & (T_SEQ-1);
    float4 wv = *(const float4*)(convW + k*4);
    float s = convb[k];
    if (t>=3) s += xsr[(bt-3)*ED_+k]*wv.x;
    if (t>=2) s += xsr[(bt-2)*ED_+k]*wv.y;
    if (t>=1) s += xsr[(bt-1)*ED_+k]*wv.z;
    s += xsr[bt*ED_+k]*wv.w;
    at[k][r] = s * sigmoidf_(s);
  }
  __syncthreads();
  float acc[8];
  #pragma unroll
  for (int r=0;r<8;r++) acc[r]=0.f;
  int c = tid;
  for (int k=0;k<256;k++){
    float w = WcT[k*384 + c];            // coalesced
    float a[8];
    *(float4*)&a[0] = *(const float4*)&at[k][0];   // broadcast
    *(float4*)&a[4] = *(const float4*)&at[k][4];
    #pragma unroll
    for (int r=0;r<8;r++) acc[r] = fmaf(a[r], w, acc[r]);
  }
  int b4 = bt0 >> 10, tb = bt0 & (T_SEQ-1);
  if (c < 256){
    float bcv = dtb[c];
    float2* pout = (float2*)dxp + (size_t)(b4*ED_ + c)*T_SEQ + tb;
    #pragma unroll
    for (int r=0;r<8;r++){
      float xv = acc[r] + bcv;
      float dv = (xv > 20.f) ? xv : log1pf(__expf(xv));
      pout[r] = make_float2(dv, dv * at[c][r]);   // {delta, delta*xs}
    }
  } else if (c < 320){
    #pragma unroll
    for (int r=0;r<8;r++) bcf[((size_t)(bt0+r)*NS + (c-256))*2 + 0] = acc[r];
  } else {
    #pragma unroll
    for (int r=0;r<8;r++) bcf[((size_t)(bt0+r)*NS + (c-320))*2 + 1] = acc[r];
  }
}

// K5: chunked scan — R6 configuration (measured best 63.9us): 4 chunks x 256 t,
// 256-thr block per (b,e), grid 1024, launch_bounds(256,4). R7 proved more
// waves don't help (issue-bound): 8-wave variant regressed to 66.8us.
__global__ __launch_bounds__(256,4) void k5_scan(const float* dxpf, const float* bcf,
                                                  const float* Alog, float* yrT){
  __shared__ float lcar[3][64], lapr[3][64];
  int i = blockIdx.x;
  int w = threadIdx.x >> 6;      // chunk 0..3
  int n = threadIdx.x & 63;      // state index (lane)
  int x = i & 7;                 // XCD swizzle
  int r = i >> 3;
  int b = r & 3;
  int g = r >> 2;                // 0..31
  int e = x*32 + g;
  const int CH = T_SEQ/4;        // 256
  int t0 = w*CH;
  float A2 = -__expf(Alog[e*NS+n]) * LOG2E;
  const float2* pd  = (const float2*)dxpf + (size_t)(b*ED_ + e)*T_SEQ + t0;  // lane=t
  const float2* pbc = (const float2*)bcf  + (size_t)(b*T_SEQ + t0)*NS + n;   // lane=n
  float*        py  = yrT + (size_t)(b*ED_ + e)*T_SEQ + t0;

  // ---- phase 1: carry-only scan (waves 0..2)
  if (w < 3){
    float h = 0.f, Ssum = 0.f;
    float2 dxc = pd[n];
    for (int sb=0; sb<CH; sb+=64){
      float2 dxn = dxc;
      if (sb+64 < CH) dxn = pd[sb+64+n];
      float sv = dxc.x;
      DPP6(sv);
      Ssum += rlane_(sv, 63);
      float bA[8], bB[8];
      #pragma unroll
      for (int j=0;j<8;j++) bA[j] = pbc[(sb+j)*NS].x;
      #pragma unroll
      for (int bb=0; bb<64; bb+=16){
        #pragma unroll
        for (int j=0;j<8;j++) bB[j] = pbc[(sb+bb+8+j)*NS].x;
        #pragma unroll
        for (int j=0;j<8;j++){
          float sd = rlane_(dxc.x, bb+j);
          float su = rlane_(dxc.y, bb+j);
          h = fmaf(exp2_(sd*A2), h, su*bA[j]);
        }
        if (bb+16 < 64){
          #pragma unroll
          for (int j=0;j<8;j++) bA[j] = pbc[(sb+bb+16+j)*NS].x;
        }
        #pragma unroll
        for (int j=0;j<8;j++){
          float sd = rlane_(dxc.x, bb+8+j);
          float su = rlane_(dxc.y, bb+8+j);
          h = fmaf(exp2_(sd*A2), h, su*bB[j]);
        }
      }
      dxc = dxn;
    }
    lcar[w][n] = h;
    lapr[w][n] = exp2_(A2*Ssum);
  }
  __syncthreads();

  // ---- combine: h_in for this wave's chunk
  float h = 0.f;
  if (w >= 1) h = lcar[0][n];
  if (w >= 2) h = fmaf(lapr[1][n], h, lcar[1][n]);
  if (w >= 3) h = fmaf(lapr[2][n], h, lcar[2][n]);

  // ---- phase 2: full output scan
  {
    float2 dxc = pd[n];
    for (int sb=0; sb<CH; sb+=64){
      float2 dxn = dxc;
      if (sb+64 < CH) dxn = pd[sb+64+n];
      int accI = 0;
      float2 cA[8], cB[8];
      #pragma unroll
      for (int j=0;j<8;j++) cA[j] = pbc[(sb+j)*NS];
      #pragma unroll
      for (int bb=0; bb<64; bb+=16){
        #pragma unroll
        for (int j=0;j<8;j++) cB[j] = pbc[(sb+bb+8+j)*NS];
        #pragma unroll
        for (int j=0;j<8;j++){
          float sd = rlane_(dxc.x, bb+j);
          float su = rlane_(dxc.y, bb+j);
          h = fmaf(exp2_(sd*A2), h, su*cA[j].x);
          float pp = h*cA[j].y;
          DPP6(pp);
          collect_(accI, pp, bb+j);
        }
        if (bb+16 < 64){
          #pragma unroll
          for (int j=0;j<8;j++) cA[j] = pbc[(sb+bb+16+j)*NS];
        }
        #pragma unroll
        for (int j=0;j<8;j++){
          float sd = rlane_(dxc.x, bb+8+j);
          float su = rlane_(dxc.y, bb+8+j);
          h = fmaf(exp2_(sd*A2), h, su*cB[j].x);
          float pp = h*cB[j].y;
          DPP6(pp);
          collect_(accI, pp, bb+8+j);
        }
      }
      py[sb+n] = __int_as_float(accI);
      dxc = dxn;
    }
  }
}

// K6: stage yrT (e-major) + xs = u/delta from dxpT via LDS; combine with gate;
// then out = LayerNorm(y @ out_proj_W.T + 2*z)*ln_w + ln_b. (unchanged; will
// fix its weight coalescing once counters surface it)
__global__ __launch_bounds__(256) void k6_out(const float* yrT, const float* dxpf, const float* zg,
                                               const float* Dp, const float* W, const float* z,
                                               const float* lnw, const float* lnb, float* out){
  __shared__ float yt[256][8];
  __shared__ float xst[256][8];
  __shared__ float psum[4][4], psq[4][4];
  int bt0 = blockIdx.x*8; int tid = threadIdx.x;
  int b4 = bt0 >> 10, tb = bt0 & (T_SEQ-1);
  int el = tid>>3, tl = tid&7;
  #pragma unroll
  for (int gg=0; gg<8; gg++){
    int ee = el + gg*32;
    size_t base = (size_t)(b4*ED_ + ee)*T_SEQ + tb + tl;
    float2 du = ((const float2*)dxpf)[base];
    yt[ee][tl]  = yrT[base];
    xst[ee][tl] = du.y / du.x;        // xs = (delta*xs)/delta; delta >= softplus(-4) ~ 0.018
  }
  __syncthreads();
  for (int i=tid;i<2048;i+=256){
    int rr=i>>8, k=i&255; int bt=bt0+rr;
    float zgv = zg[bt*ED_ + k];
    float yv  = yt[k][rr] + Dp[k]*xst[k][rr];
    yt[k][rr] = yv * zgv * sigmoidf_(zgv);
  }
  __syncthreads();
  int d = tid & 127, gdx = tid>>7;
  float acc[4] = {0.f,0.f,0.f,0.f};
  for (int k=0;k<256;k+=4){
    float4 wv = *(const float4*)(W + d*256 + k);
    float w[4] = {wv.x, wv.y, wv.z, wv.w};
    #pragma unroll
    for (int kk=0;kk<4;kk++){
      float4 q = *(const float4*)&yt[k+kk][gdx*4];
      acc[0] = fmaf(q.x, w[kk], acc[0]);
      acc[1] = fmaf(q.y, w[kk], acc[1]);
      acc[2] = fmaf(q.z, w[kk], acc[2]);
      acc[3] = fmaf(q.w, w[kk], acc[3]);
    }
  }
  float val[4];
  #pragma unroll
  for (int j=0;j<4;j++){
    int bt = bt0 + gdx*4 + j;
    val[j] = acc[j] + 2.f*z[bt*DM + d];
  }
  int w_id = tid>>6;
  #pragma unroll
  for (int j=0;j<4;j++){
    float s = val[j], q = val[j]*val[j];
    #pragma unroll
    for (int off=32; off>=1; off>>=1){ s += __shfl_down(s, off); q += __shfl_down(q, off); }
    if ((tid&63)==0){ psum[w_id][j]=s; psq[w_id][j]=q; }
  }
  __syncthreads();
  float lw = lnw[d], lb = lnb[d];
  #pragma unroll
  for (int j=0;j<4;j++){
    int bt = bt0 + gdx*4 + j;
    float sum = psum[gdx*2][j] + psum[gdx*2+1][j];
    float sq  = psq [gdx*2][j] + psq [gdx*2+1][j];
    float mu  = sum*(1.f/DM);
    float var = sq*(1.f/DM) - mu*mu;
    float inv = rsqrtf(var + 1e-5f);
    out[bt*DM + d] = (val[j]-mu)*inv*lw + lb;
  }
}

extern "C" void kernel_launch(void* const* d_in, const int* in_sizes, int n_in,
                              void* d_out, int out_size, void* d_ws, size_t ws_size,
                              hipStream_t stream){
  const float* zseq = (const float*)d_in[0];
  const float* aux  = (const float*)d_in[1];
  const float* auxW = (const float*)d_in[2];
  const float* auxb = (const float*)d_in[3];
  const float* lnw  = (const float*)d_in[4];
  const float* lnb  = (const float*)d_in[5];
  const float* rmsw = (const float*)d_in[6];
  const float* inW  = (const float*)d_in[7];
  const float* convW= (const float*)d_in[8];
  const float* convb= (const float*)d_in[9];
  const float* xpW  = (const float*)d_in[10];
  const float* dtW  = (const float*)d_in[11];
  const float* dtb  = (const float*)d_in[12];
  const float* Alog = (const float*)d_in[13];
  const float* Dp   = (const float*)d_in[14];
  const float* outW = (const float*)d_in[15];
  float* out = (float*)d_out;
  float* ws = (float*)d_ws;

  float* z   = ws+OFF_Z;
  float* zg  = ws+OFF_ZG;
  float* xsr = ws+OFF_XSR;
  float* WcT = ws+OFF_WC;
  float* yr  = ws+OFF_YR;
  float* wti = ws+OFF_YR;    // WTi hosted in YR head; dead before k5 writes yr
  float* dxp = ws+OFF_DPX;
  float* bcp = ws+OFF_BC;

  k0_t     <<<128,256,0,stream>>>(inW, wti);
  k2_fused <<<896,256,0,stream>>>(zseq,aux,auxW,auxb,rmsw,wti,xpW,dtW,z,xsr,zg,WcT);
  k4b_xproj<<<512,384,0,stream>>>(xsr,convW,convb,WcT,dtb,dxp,bcp);
  k5_scan  <<<1024,256,0,stream>>>(dxp,bcp,Alog,yr);
  k6_out   <<<512,256,0,stream>>>(yr,dxp,zg,Dp,outW,z,lnw,lnb,out);
}

// Round 10
// 206.025 us; speedup vs baseline: 1.0892x; 1.0099x over previous
//
#include <hip/hip_runtime.h>
#include <hip/hip_bf16.h>

#define B_SZ 4
#define T_SEQ 1024
#define DM 128
#define ED_ 256
#define NS 64
#define LOG2E 1.44269504088896340736f

// workspace layout (float elements). Total = 6,389,760 floats = 25.6 MB (accepted size).
// dxpT is TRANSPOSED [b][e][t] x {delta, delta*xs}; yrT is TRANSPOSED [b][e][t].
// WTi (in_proj transposed) lives in the YR head: k0 -> k2, dead before k5 writes YR.
// WoT (out_proj transposed, 32K floats) lives in the XSR head: written by k5's
// extra blocks (xsr is dead after k4b), read by k6. Zero extra space, zero launches.
#define OFF_Z      0u         /* 524288  f32  z (residual, read by K6)            */
#define OFF_ZG     524288u    /* 1048576 f32  gate (k2 -> k6)                     */
#define OFF_XSR    1572864u   /* 1048576 f32  conv input (k2 -> k4b); head=WoT    */
#define OFF_WC     2621440u   /* 98304   f32  WcT[k][c] transposed combined wt    */
#define OFF_YR     2719744u   /* 1048576 f32  scan out [b][e][t]; head hosts WTi  */
#define OFF_DPX    3768320u   /* 2097152 f32  {delta, delta*xs} [b][e][t] pairs   */
#define OFF_BC     5865472u   /* 524288  f32  {B, C} [b][t][n] pairs (k4b -> k5)  */

__device__ __forceinline__ float sigmoidf_(float x){ return 1.f/(1.f+__expf(-x)); }
__device__ __forceinline__ float exp2_(float x){ return __builtin_amdgcn_exp2f(x); }
__device__ __forceinline__ float rlane_(float v, int l){
  return __int_as_float(__builtin_amdgcn_readlane(__float_as_int(v), l));
}
// collect: accI[lane t] = total of pp (total sits in lane 63 after DPP6).
// v_writelane reads ONE SGPR max -> lane select must be an immediate.
__device__ __forceinline__ void collect_(int &accI, float pp, int t){
  int s;
  asm("v_readlane_b32 %0, %1, 63" : "=s"(s) : "v"(__float_as_int(pp)));
  asm("v_writelane_b32 %0, %1, %2" : "+v"(accI) : "s"(s), "i"(t));
}

// Fused DPP add: p += dpp(p) in ONE instruction. bound_ctrl:0 => invalid lanes read 0.
#define DPPR(p, ctl) asm("v_add_f32_dpp %0, %0, %0 " ctl " row_mask:0xf bank_mask:0xf bound_ctrl:0" : "+v"(p))
#define DPP6(p) do{ DPPR(p,"row_shr:1"); DPPR(p,"row_shr:2"); DPPR(p,"row_shr:4"); \
                    DPPR(p,"row_shr:8"); DPPR(p,"row_bcast:15"); DPPR(p,"row_bcast:31"); }while(0)

// K0: transpose in_proj W (512x128 row-major) -> WTi[k][c] (128x512).
__global__ __launch_bounds__(256) void k0_t(const float* W, float* WTi){
  int k = blockIdx.x;        // 0..127
  int c = threadIdx.x;       // 0..255
  WTi[k*512 + c]       = W[(size_t)c*128 + k];
  WTi[k*512 + c + 256] = W[(size_t)(c+256)*128 + k];
}

// K2f: blocks 0..511: fused [z = zseq+aux@auxW.T+auxb ; zn=RMSNorm(z)*rms_w] -> LDS,
//      then xz = zn @ in_proj_W.T -> xsr | zg, reading WTi[k][c] COALESCED.
//      blocks 512..895: build WcT[k][c] (transposed combined x_proj/dt weight).
__global__ __launch_bounds__(256) void k2_fused(const float* zseq, const float* aux, const float* auxW,
                                                const float* auxb, const float* rmsw, const float* WTi,
                                                const float* xprojW, const float* dtW,
                                                float* z, float* xsr, float* zg, float* WcT){
  if (blockIdx.x >= 512){
    int r = blockIdx.x - 512; int k = threadIdx.x;
    float v;
    if (r < 256){
      v = 0.f;
      #pragma unroll
      for (int j=0;j<8;j++) v += dtW[r*8+j] * xprojW[j*256+k];
    } else {
      v = xprojW[(8 + r-256)*256 + k];
    }
    WcT[k*384 + r] = v;      // transposed store (uncoalesced but one-off)
    return;
  }
  __shared__ float at[128][8];
  int bt0 = blockIdx.x*8; int tid = threadIdx.x;
  {
    int r = tid>>5, l = tid&31;
    int bt = bt0 + r;
    float a0 = aux[bt*3+0], a1 = aux[bt*3+1], a2 = aux[bt*3+2];
    float zv[4]; float ssq = 0.f;
    #pragma unroll
    for (int j=0;j<4;j++){
      int d = l + 32*j;
      float v = zseq[bt*DM+d] + a0*auxW[d*3+0] + a1*auxW[d*3+1] + a2*auxW[d*3+2] + auxb[d];
      zv[j] = v; ssq += v*v;
    }
    #pragma unroll
    for (int m=16;m>=1;m>>=1) ssq += __shfl_xor(ssq, m);
    float rinv = rsqrtf(ssq*(1.f/DM) + 1e-5f);
    #pragma unroll
    for (int j=0;j<4;j++){
      int d = l + 32*j;
      z[bt*DM+d] = zv[j];
      at[d][r] = zv[j]*rinv*rmsw[d];
    }
  }
  __syncthreads();
  float acc0[8], acc1[8];
  #pragma unroll
  for (int r=0;r<8;r++){ acc0[r]=0.f; acc1[r]=0.f; }
  int c0 = tid;
  for (int k=0;k<128;k++){
    float w0 = WTi[k*512 + c0];          // coalesced: lanes -> consecutive floats
    float w1 = WTi[k*512 + c0 + 256];
    float a[8];
    *(float4*)&a[0] = *(const float4*)&at[k][0];   // broadcast b128 (conflict-free)
    *(float4*)&a[4] = *(const float4*)&at[k][4];
    #pragma unroll
    for (int r=0;r<8;r++){ acc0[r] = fmaf(a[r], w0, acc0[r]); acc1[r] = fmaf(a[r], w1, acc1[r]); }
  }
  #pragma unroll
  for (int r=0;r<8;r++){
    int bt = bt0+r;
    xsr[bt*ED_ + c0] = acc0[r];
    zg [bt*ED_ + c0] = acc1[r];
  }
}

// K4b: conv(k=4)+bias+SiLU from xsr (LDS), then [delta_pre | B | C] = xs @ WcT.
// Weight reads COALESCED (WcT[k][c], c=tid).
__global__ __launch_bounds__(384) void k4b_xproj(const float* xsr, const float* convW, const float* convb,
                                                 const float* WcT, const float* dtb,
                                                 float* dxp, float* bcf){
  __shared__ float at[256][8];
  int bt0 = blockIdx.x*8; int tid = threadIdx.x;
  for (int i=tid;i<2048;i+=384){
    int r=i>>8,k=i&255; int bt=bt0+r; int t = bt & (T_SEQ-1);
    float4 wv = *(const float4*)(convW + k*4);
    float s = convb[k];
    if (t>=3) s += xsr[(bt-3)*ED_+k]*wv.x;
    if (t>=2) s += xsr[(bt-2)*ED_+k]*wv.y;
    if (t>=1) s += xsr[(bt-1)*ED_+k]*wv.z;
    s += xsr[bt*ED_+k]*wv.w;
    at[k][r] = s * sigmoidf_(s);
  }
  __syncthreads();
  float acc[8];
  #pragma unroll
  for (int r=0;r<8;r++) acc[r]=0.f;
  int c = tid;
  for (int k=0;k<256;k++){
    float w = WcT[k*384 + c];            // coalesced
    float a[8];
    *(float4*)&a[0] = *(const float4*)&at[k][0];   // broadcast
    *(float4*)&a[4] = *(const float4*)&at[k][4];
    #pragma unroll
    for (int r=0;r<8;r++) acc[r] = fmaf(a[r], w, acc[r]);
  }
  int b4 = bt0 >> 10, tb = bt0 & (T_SEQ-1);
  if (c < 256){
    float bcv = dtb[c];
    float2* pout = (float2*)dxp + (size_t)(b4*ED_ + c)*T_SEQ + tb;
    #pragma unroll
    for (int r=0;r<8;r++){
      float xv = acc[r] + bcv;
      float dv = (xv > 20.f) ? xv : log1pf(__expf(xv));
      pout[r] = make_float2(dv, dv * at[c][r]);   // {delta, delta*xs}
    }
  } else if (c < 320){
    #pragma unroll
    for (int r=0;r<8;r++) bcf[((size_t)(bt0+r)*NS + (c-256))*2 + 0] = acc[r];
  } else {
    #pragma unroll
    for (int r=0;r<8;r++) bcf[((size_t)(bt0+r)*NS + (c-320))*2 + 1] = acc[r];
  }
}

// K5: chunked scan — R6 configuration (measured best 63.9us): 4 chunks x 256 t,
// 256-thr block per (b,e), launch_bounds(256,4). Blocks 1024..1055 instead
// transpose out_proj W -> WoT[k][d] into the dead XSR head for k6 (no race:
// xsr is read only by k4b; scan blocks read dxp/bc/Alog only).
__global__ __launch_bounds__(256,4) void k5_scan(const float* dxpf, const float* bcf,
                                                  const float* Alog, float* yrT,
                                                  const float* outW, float* wot){
  if (blockIdx.x >= 1024){
    int bb = blockIdx.x - 1024;          // 0..31
    int k  = bb*8 + (threadIdx.x>>5);    // 0..255
    int d  = (threadIdx.x&31)*4;         // 0..124
    float4 v;
    v.x = outW[(d+0)*256 + k];
    v.y = outW[(d+1)*256 + k];
    v.z = outW[(d+2)*256 + k];
    v.w = outW[(d+3)*256 + k];
    *(float4*)&wot[k*128 + d] = v;
    return;
  }
  __shared__ float lcar[3][64], lapr[3][64];
  int i = blockIdx.x;
  int w = threadIdx.x >> 6;      // chunk 0..3
  int n = threadIdx.x & 63;      // state index (lane)
  int x = i & 7;                 // XCD swizzle
  int r = i >> 3;
  int b = r & 3;
  int g = r >> 2;                // 0..31
  int e = x*32 + g;
  const int CH = T_SEQ/4;        // 256
  int t0 = w*CH;
  float A2 = -__expf(Alog[e*NS+n]) * LOG2E;
  const float2* pd  = (const float2*)dxpf + (size_t)(b*ED_ + e)*T_SEQ + t0;  // lane=t
  const float2* pbc = (const float2*)bcf  + (size_t)(b*T_SEQ + t0)*NS + n;   // lane=n
  float*        py  = yrT + (size_t)(b*ED_ + e)*T_SEQ + t0;

  // ---- phase 1: carry-only scan (waves 0..2)
  if (w < 3){
    float h = 0.f, Ssum = 0.f;
    float2 dxc = pd[n];
    for (int sb=0; sb<CH; sb+=64){
      float2 dxn = dxc;
      if (sb+64 < CH) dxn = pd[sb+64+n];
      float sv = dxc.x;
      DPP6(sv);
      Ssum += rlane_(sv, 63);
      float bA[8], bB[8];
      #pragma unroll
      for (int j=0;j<8;j++) bA[j] = pbc[(sb+j)*NS].x;
      #pragma unroll
      for (int bb=0; bb<64; bb+=16){
        #pragma unroll
        for (int j=0;j<8;j++) bB[j] = pbc[(sb+bb+8+j)*NS].x;
        #pragma unroll
        for (int j=0;j<8;j++){
          float sd = rlane_(dxc.x, bb+j);
          float su = rlane_(dxc.y, bb+j);
          h = fmaf(exp2_(sd*A2), h, su*bA[j]);
        }
        if (bb+16 < 64){
          #pragma unroll
          for (int j=0;j<8;j++) bA[j] = pbc[(sb+bb+16+j)*NS].x;
        }
        #pragma unroll
        for (int j=0;j<8;j++){
          float sd = rlane_(dxc.x, bb+8+j);
          float su = rlane_(dxc.y, bb+8+j);
          h = fmaf(exp2_(sd*A2), h, su*bB[j]);
        }
      }
      dxc = dxn;
    }
    lcar[w][n] = h;
    lapr[w][n] = exp2_(A2*Ssum);
  }
  __syncthreads();

  // ---- combine: h_in for this wave's chunk
  float h = 0.f;
  if (w >= 1) h = lcar[0][n];
  if (w >= 2) h = fmaf(lapr[1][n], h, lcar[1][n]);
  if (w >= 3) h = fmaf(lapr[2][n], h, lcar[2][n]);

  // ---- phase 2: full output scan
  {
    float2 dxc = pd[n];
    for (int sb=0; sb<CH; sb+=64){
      float2 dxn = dxc;
      if (sb+64 < CH) dxn = pd[sb+64+n];
      int accI = 0;
      float2 cA[8], cB[8];
      #pragma unroll
      for (int j=0;j<8;j++) cA[j] = pbc[(sb+j)*NS];
      #pragma unroll
      for (int bb=0; bb<64; bb+=16){
        #pragma unroll
        for (int j=0;j<8;j++) cB[j] = pbc[(sb+bb+8+j)*NS];
        #pragma unroll
        for (int j=0;j<8;j++){
          float sd = rlane_(dxc.x, bb+j);
          float su = rlane_(dxc.y, bb+j);
          h = fmaf(exp2_(sd*A2), h, su*cA[j].x);
          float pp = h*cA[j].y;
          DPP6(pp);
          collect_(accI, pp, bb+j);
        }
        if (bb+16 < 64){
          #pragma unroll
          for (int j=0;j<8;j++) cA[j] = pbc[(sb+bb+16+j)*NS];
        }
        #pragma unroll
        for (int j=0;j<8;j++){
          float sd = rlane_(dxc.x, bb+8+j);
          float su = rlane_(dxc.y, bb+8+j);
          h = fmaf(exp2_(sd*A2), h, su*cB[j].x);
          float pp = h*cB[j].y;
          DPP6(pp);
          collect_(accI, pp, bb+8+j);
        }
      }
      py[sb+n] = __int_as_float(accI);
      dxc = dxn;
    }
  }
}

// K6: stage yrT (e-major) + xs = u/delta from dxpT via LDS; combine with gate;
// then out = LayerNorm(y @ out_proj_W.T + 2*z)*ln_w + ln_b.
// Weight reads now COALESCED via WoT[k][d] (d=tid&127: lanes consecutive ->
// 4 lines/instr instead of 64). yt LDS reads remain wave-broadcast.
__global__ __launch_bounds__(256) void k6_out(const float* yrT, const float* dxpf, const float* zg,
                                               const float* Dp, const float* wot, const float* z,
                                               const float* lnw, const float* lnb, float* out){
  __shared__ float yt[256][8];
  __shared__ float xst[256][8];
  __shared__ float psum[4][4], psq[4][4];
  int bt0 = blockIdx.x*8; int tid = threadIdx.x;
  int b4 = bt0 >> 10, tb = bt0 & (T_SEQ-1);
  int el = tid>>3, tl = tid&7;
  #pragma unroll
  for (int gg=0; gg<8; gg++){
    int ee = el + gg*32;
    size_t base = (size_t)(b4*ED_ + ee)*T_SEQ + tb + tl;
    float2 du = ((const float2*)dxpf)[base];
    yt[ee][tl]  = yrT[base];
    xst[ee][tl] = du.y / du.x;        // xs = (delta*xs)/delta; delta >= softplus(-4) ~ 0.018
  }
  __syncthreads();
  for (int i=tid;i<2048;i+=256){
    int rr=i>>8, k=i&255; int bt=bt0+rr;
    float zgv = zg[bt*ED_ + k];
    float yv  = yt[k][rr] + Dp[k]*xst[k][rr];
    yt[k][rr] = yv * zgv * sigmoidf_(zgv);
  }
  __syncthreads();
  int d = tid & 127, gdx = tid>>7;
  float acc[4] = {0.f,0.f,0.f,0.f};
  for (int k=0;k<256;k+=4){
    float w0 = wot[(k+0)*128 + d];       // coalesced
    float w1 = wot[(k+1)*128 + d];
    float w2 = wot[(k+2)*128 + d];
    float w3 = wot[(k+3)*128 + d];
    float4 q0 = *(const float4*)&yt[k+0][gdx*4];   // broadcast
    float4 q1 = *(const float4*)&yt[k+1][gdx*4];
    float4 q2 = *(const float4*)&yt[k+2][gdx*4];
    float4 q3 = *(const float4*)&yt[k+3][gdx*4];
    acc[0] = fmaf(q0.x,w0,acc[0]); acc[1] = fmaf(q0.y,w0,acc[1]);
    acc[2] = fmaf(q0.z,w0,acc[2]); acc[3] = fmaf(q0.w,w0,acc[3]);
    acc[0] = fmaf(q1.x,w1,acc[0]); acc[1] = fmaf(q1.y,w1,acc[1]);
    acc[2] = fmaf(q1.z,w1,acc[2]); acc[3] = fmaf(q1.w,w1,acc[3]);
    acc[0] = fmaf(q2.x,w2,acc[0]); acc[1] = fmaf(q2.y,w2,acc[1]);
    acc[2] = fmaf(q2.z,w2,acc[2]); acc[3] = fmaf(q2.w,w2,acc[3]);
    acc[0] = fmaf(q3.x,w3,acc[0]); acc[1] = fmaf(q3.y,w3,acc[1]);
    acc[2] = fmaf(q3.z,w3,acc[2]); acc[3] = fmaf(q3.w,w3,acc[3]);
  }
  float val[4];
  #pragma unroll
  for (int j=0;j<4;j++){
    int bt = bt0 + gdx*4 + j;
    val[j] = acc[j] + 2.f*z[bt*DM + d];
  }
  int w_id = tid>>6;
  #pragma unroll
  for (int j=0;j<4;j++){
    float s = val[j], q = val[j]*val[j];
    #pragma unroll
    for (int off=32; off>=1; off>>=1){ s += __shfl_down(s, off); q += __shfl_down(q, off); }
    if ((tid&63)==0){ psum[w_id][j]=s; psq[w_id][j]=q; }
  }
  __syncthreads();
  float lw = lnw[d], lb = lnb[d];
  #pragma unroll
  for (int j=0;j<4;j++){
    int bt = bt0 + gdx*4 + j;
    float sum = psum[gdx*2][j] + psum[gdx*2+1][j];
    float sq  = psq [gdx*2][j] + psq [gdx*2+1][j];
    float mu  = sum*(1.f/DM);
    float var = sq*(1.f/DM) - mu*mu;
    float inv = rsqrtf(var + 1e-5f);
    out[bt*DM + d] = (val[j]-mu)*inv*lw + lb;
  }
}

extern "C" void kernel_launch(void* const* d_in, const int* in_sizes, int n_in,
                              void* d_out, int out_size, void* d_ws, size_t ws_size,
                              hipStream_t stream){
  const float* zseq = (const float*)d_in[0];
  const float* aux  = (const float*)d_in[1];
  const float* auxW = (const float*)d_in[2];
  const float* auxb = (const float*)d_in[3];
  const float* lnw  = (const float*)d_in[4];
  const float* lnb  = (const float*)d_in[5];
  const float* rmsw = (const float*)d_in[6];
  const float* inW  = (const float*)d_in[7];
  const float* convW= (const float*)d_in[8];
  const float* convb= (const float*)d_in[9];
  const float* xpW  = (const float*)d_in[10];
  const float* dtW  = (const float*)d_in[11];
  const float* dtb  = (const float*)d_in[12];
  const float* Alog = (const float*)d_in[13];
  const float* Dp   = (const float*)d_in[14];
  const float* outW = (const float*)d_in[15];
  float* out = (float*)d_out;
  float* ws = (float*)d_ws;

  float* z   = ws+OFF_Z;
  float* zg  = ws+OFF_ZG;
  float* xsr = ws+OFF_XSR;
  float* wot = ws+OFF_XSR;   // WoT hosted in XSR head; xsr dead after k4b
  float* WcT = ws+OFF_WC;
  float* yr  = ws+OFF_YR;
  float* wti = ws+OFF_YR;    // WTi hosted in YR head; dead before k5 writes yr
  float* dxp = ws+OFF_DPX;
  float* bcp = ws+OFF_BC;

  k0_t     <<<128,256,0,stream>>>(inW, wti);
  k2_fused <<<896,256,0,stream>>>(zseq,aux,auxW,auxb,rmsw,wti,xpW,dtW,z,xsr,zg,WcT);
  k4b_xproj<<<512,384,0,stream>>>(xsr,convW,convb,WcT,dtb,dxp,bcp);
  k5_scan  <<<1056,256,0,stream>>>(dxp,bcp,Alog,yr,outW,wot);
  k6_out   <<<512,256,0,stream>>>(yr,dxp,zg,Dp,wot,z,lnw,lnb,out);
}